// Round 1
// baseline (485.661 us; speedup 1.0000x reference)
//
#include <hip/hip_runtime.h>

// BlockCirculantLinear via frequency domain:
//   out[s, o*128+t] = ifft_t( sum_j fft(x_d[s,j,:]) * conj(fft(W[o,j,:])) )
// Stages: K1: DFT of x-blocks (MFMA GEMM vs cos/sin basis) -> X[f][s][jc] bf16
//         K2: per-frequency real-ified GEMM over jc (K=128) into LDS Y, then
//             inverse-DFT GEMM (K=160, zero-padded) -> out fp32. No Y in HBM.
// R1 changes: (a) K2 XCD-aware block swizzle (8 o-tiles of one s-tile -> same
//             XCD so the shared 266KB X slice is L2-local, not 8x L3);
//             (b) K1 skips the 3 all-zero n-tiles (nt 9..11);
//             (c) K2 phase-A LDS scatter: packed u32 stores + per-o XOR block
//             swizzle (was 8-way bank conflict on 2B stores).

typedef __bf16 bf16;
typedef __bf16 bf16x8 __attribute__((ext_vector_type(8)));
typedef float f32x4 __attribute__((ext_vector_type(4)));

#define PI_F 3.14159265358979323846f

// ws layout (bytes)
#define WS_B1   0u          // [192 fc][128 t] bf16 = 49152
#define WS_B2T  49152u      // [128 t][160 fc] bf16 = 40960
#define WS_WMAT 90112u      // [65 f][128 oc][128 jc] bf16 = 2129920
#define WS_X    2220032u    // [65 f][4096 s][128 jc] bf16 = 68157440

__device__ __forceinline__ unsigned int pack_bf2(float a, float b) {
    unsigned short ra = __builtin_bit_cast(unsigned short, (bf16)a);
    unsigned short rb = __builtin_bit_cast(unsigned short, (bf16)b);
    return (unsigned int)ra | ((unsigned int)rb << 16);
}

// ---------------- init: DFT bases ----------------
// B1[fc][t]: fc=2f+c; c=0 -> cos(2pi f t/128), c=1 -> -sin(...). Rows f>64 zero.
// B2T[t][fc]: inverse-rfft coefficients; fc>=130 zero (padding for K=160 loop).
__global__ __launch_bounds__(256) void init_basis(bf16* __restrict__ B1,
                                                  bf16* __restrict__ B2T) {
    int gid = blockIdx.x * 256 + threadIdx.x;
    if (gid < 192 * 128) {
        int fc = gid >> 7, t = gid & 127;
        int f = fc >> 1;
        float v = 0.f;
        if (f <= 64) {
            int a = (f * t) & 127;
            float ang = a * (PI_F / 64.f);
            v = (fc & 1) ? -__sinf(ang) : __cosf(ang);
        }
        B1[gid] = (bf16)v;
    }
    if (gid < 128 * 160) {
        int t = gid / 160, fc = gid % 160;
        int f = fc >> 1, c = fc & 1;
        float v = 0.f;
        if (f == 0) {
            v = c ? 0.f : (1.f / 128.f);
        } else if (f == 64) {
            v = c ? 0.f : ((t & 1) ? -1.f / 128.f : 1.f / 128.f);
        } else if (f < 64) {
            int a = (f * t) & 127;
            float ang = a * (PI_F / 64.f);
            v = c ? (-2.f / 128.f) * __sinf(ang) : (2.f / 128.f) * __cosf(ang);
        }
        B2T[gid] = (bf16)v;
    }
}

// ---------------- init: frequency-domain weights ----------------
// Wr[o,j,f] = sum_tau W cos, Wi = +sum_tau W sin  (== conj(fft(W)))
// Wmat[f][2o+0][2j+0]=Wr  [2o+0][2j+1]=-Wi  [2o+1][2j+0]=Wi  [2o+1][2j+1]=Wr
__global__ __launch_bounds__(256) void init_wmat(const float* __restrict__ W,
                                                 bf16* __restrict__ Wm) {
    __shared__ float ct[128], st[128];
    const int tid = threadIdx.x;
    if (tid < 128) {
        float ang = tid * (PI_F / 64.f);
        ct[tid] = __cosf(ang);
        st[tid] = __sinf(ang);
    }
    __syncthreads();
    int gid = blockIdx.x * 256 + tid;
    if (gid >= 65 * 4096) return;
    int f = gid >> 12;
    int rem = gid & 4095;
    int o = rem >> 6, j = rem & 63;
    const float* wp = W + (((o << 6) + j) << 7);
    float wr = 0.f, wi = 0.f;
    for (int tau = 0; tau < 128; tau++) {
        float w = wp[tau];
        int a = (f * tau) & 127;
        wr += w * ct[a];
        wi += w * st[a];
    }
    bf16* base = Wm + ((size_t)f * 128 + 2 * o) * 128 + 2 * j;
    base[0]   = (bf16)wr;
    base[1]   = (bf16)(-wi);
    base[128] = (bf16)wi;
    base[129] = (bf16)wr;
}

// ---------------- K1: DFT of x-blocks ----------------
// grid 512: blockIdx = s_tile(256) * 2 + j_half. block 256 (4 waves).
// Per 8-j round: stage x*D (fp32->bf16) to LDS, waves compute live fc n-tiles
// (nt = wave+4t; nt 9..11 are all-zero B1 rows -> skipped; only wave 0 runs
// t=2 for nt=8 which holds f=64), then XOR-1 lane exchange pairs (re,im) and
// stores 16B/lane to X[f][s][jc].
__global__ __launch_bounds__(256) void k1_dft(const float* __restrict__ x,
                                              const float* __restrict__ D,
                                              const bf16* __restrict__ B1,
                                              bf16* __restrict__ X) {
    __shared__ bf16 xs[8][16][136];
    const int tid = threadIdx.x;
    const int wave = tid >> 6, lane = tid & 63;
    const int q = lane >> 4, nl = lane & 15;
    const int s_t = blockIdx.x >> 1, jh = blockIdx.x & 1;
    const int s0 = s_t * 16;
    const bool nt2 = (wave == 0);  // t=2 live only for wave 0 (nt=8)

    // constant B-fragments (B1 rows fc>=144 are all zero -> not loaded)
    bf16x8 bfrag[3][4];
#pragma unroll
    for (int t = 0; t < 2; t++) {
        int nt = wave + 4 * t;
#pragma unroll
        for (int kc = 0; kc < 4; kc++)
            bfrag[t][kc] = *(const bf16x8*)(B1 + (nt * 16 + nl) * 128 + kc * 32 + q * 8);
    }
    if (nt2) {
#pragma unroll
        for (int kc = 0; kc < 4; kc++)
            bfrag[2][kc] = *(const bf16x8*)(B1 + (128 + nl) * 128 + kc * 32 + q * 8);
    }

    for (int grp = 0; grp < 4; grp++) {
        const int jb = jh * 32 + grp * 8;
        __syncthreads();
        {   // stage 8 j-blocks: 8*16*128 fp32 -> bf16 (apply diagonal D)
            const int jl = tid >> 5, ss = (tid >> 1) & 15, th = tid & 1;
            const float* xp = x + (size_t)(s0 + ss) * 8192 + (jb + jl) * 128 + th * 64;
            const float* Dp = D + (jb + jl) * 128 + th * 64;
            bf16* dst = &xs[jl][ss][th * 64];
#pragma unroll
            for (int u = 0; u < 8; u++) {
                float4 a  = *(const float4*)(xp + u * 8);
                float4 b  = *(const float4*)(xp + u * 8 + 4);
                float4 da = *(const float4*)(Dp + u * 8);
                float4 db = *(const float4*)(Dp + u * 8 + 4);
                bf16x8 o;
                o[0] = (bf16)(a.x * da.x); o[1] = (bf16)(a.y * da.y);
                o[2] = (bf16)(a.z * da.z); o[3] = (bf16)(a.w * da.w);
                o[4] = (bf16)(b.x * db.x); o[5] = (bf16)(b.y * db.y);
                o[6] = (bf16)(b.z * db.z); o[7] = (bf16)(b.w * db.w);
                *(bf16x8*)(dst + u * 8) = o;
            }
        }
        __syncthreads();

        f32x4 acc[3][8];
        const f32x4 zero = {0.f, 0.f, 0.f, 0.f};
#pragma unroll
        for (int t = 0; t < 3; t++)
#pragma unroll
            for (int j = 0; j < 8; j++) acc[t][j] = zero;

        // main pass: 2 live n-tiles for every wave (branch-free hot loop)
#pragma unroll
        for (int j = 0; j < 8; j++) {
#pragma unroll
            for (int kc = 0; kc < 4; kc++) {
                bf16x8 a = *(const bf16x8*)&xs[j][nl][kc * 32 + q * 8];
                acc[0][j] = __builtin_amdgcn_mfma_f32_16x16x32_bf16(
                    a, bfrag[0][kc], acc[0][j], 0, 0, 0);
                acc[1][j] = __builtin_amdgcn_mfma_f32_16x16x32_bf16(
                    a, bfrag[1][kc], acc[1][j], 0, 0, 0);
            }
        }
        if (nt2) {  // wave 0 only: nt=8 tile (f=64)
#pragma unroll
            for (int j = 0; j < 8; j++) {
#pragma unroll
                for (int kc = 0; kc < 4; kc++) {
                    bf16x8 a = *(const bf16x8*)&xs[j][nl][kc * 32 + q * 8];
                    acc[2][j] = __builtin_amdgcn_mfma_f32_16x16x32_bf16(
                        a, bfrag[2][kc], acc[2][j], 0, 0, 0);
                }
            }
        }

        // register transpose + store: lane pair (fc even/odd) = (re, im)
        const int par = lane & 1;
#pragma unroll
        for (int t = 0; t < 3; t++) {
            if (t == 2 && !nt2) continue;  // wave-uniform skip of dead tiles
            const int fc = (wave + 4 * t) * 16 + nl;
            const int fpr = fc >> 1;
            const bool wr = (fc < 130);
#pragma unroll
            for (int r = 0; r < 4; r++) {
                float sh[8];
#pragma unroll
                for (int j = 0; j < 8; j++)
                    sh[j] = __shfl_xor(acc[t][j][r], 1);
                unsigned int d0, d1, d2, d3;
                if (!par) {
                    d0 = pack_bf2(acc[t][0][r], sh[0]);
                    d1 = pack_bf2(acc[t][1][r], sh[1]);
                    d2 = pack_bf2(acc[t][2][r], sh[2]);
                    d3 = pack_bf2(acc[t][3][r], sh[3]);
                } else {
                    d0 = pack_bf2(sh[4], acc[t][4][r]);
                    d1 = pack_bf2(sh[5], acc[t][5][r]);
                    d2 = pack_bf2(sh[6], acc[t][6][r]);
                    d3 = pack_bf2(sh[7], acc[t][7][r]);
                }
                if (wr) {
                    char* p = (char*)X + ((size_t)fpr * 4096 + s0 + q * 4 + r) * 256
                              + jb * 4 + par * 16;
                    *(uint4*)p = make_uint4(d0, d1, d2, d3);
                }
            }
        }
    }
}

// ---------------- K2: per-frequency contraction + inverse DFT ----------------
// grid 2048, XCD-swizzled: the 8 o_tiles of one s_tile are 8 CONSECUTIVE
// blocks on ONE XCD (dispatch round-robins blockIdx%8 across the 8 XCDs),
// so the shared 266KB X[f][s0:s0+16][:] slice is fetched from L3 once and
// re-read 7x from the XCD-local L2; Wmat (2.1MB) stays L2-resident.
// Phase A: wave w handles f = grp*4+w; C[m=oc16][n=s16] = Wmat[f] * X[f]^T,
//          frags straight from global, scatter into LDS Y[o][s][fc] with
//          per-o XOR block swizzle (kills the 8-way write bank conflict).
// Phase B: per (o, t-tile): out[s,t] = Y[s][o][:] * B2T (K=160; rows>=130 = 0),
//          reads apply the same uniform XOR on the 8-elem block index.
__global__ __launch_bounds__(256) void k2_gemm(const bf16* __restrict__ X,
                                               const bf16* __restrict__ Wmat,
                                               const bf16* __restrict__ B2T,
                                               float* __restrict__ out) {
    __shared__ bf16 ybuf[8 * 16 * 136 + 32];  // [o][s][fc136] + overrun pad
    const int tid = threadIdx.x;
    const int wave = tid >> 6, lane = tid & 63;
    const int q = lane >> 4, nl = lane & 15;
    // XCD-aware swizzle (bijective: 2048 = 8 XCD * 256 blocks/XCD)
    const int bid = blockIdx.x;
    const int xcd = bid & 7, seq = bid >> 3;
    const int s_t = xcd + 8 * (seq >> 3);
    const int o_t = seq & 7;
    const int s0 = s_t * 16;

    {   // zero (covers fc 130..135 pad + masked freqs)
        unsigned int* yz = (unsigned int*)ybuf;
        for (int i = tid; i < (8 * 16 * 136 + 32) / 2; i += 256) yz[i] = 0u;
    }
    __syncthreads();

    for (int grp = 0; grp < 17; grp++) {
        const int f = grp * 4 + wave;
        if (f < 65) {
            f32x4 acc = {0.f, 0.f, 0.f, 0.f};
#pragma unroll
            for (int kc = 0; kc < 4; kc++) {
                bf16x8 a = *(const bf16x8*)(Wmat + ((size_t)f * 128 + o_t * 16 + nl) * 128
                                            + kc * 32 + q * 8);
                bf16x8 b = *(const bf16x8*)(X + ((size_t)f * 4096 + s0 + nl) * 128
                                            + kc * 32 + q * 8);
                acc = __builtin_amdgcn_mfma_f32_16x16x32_bf16(a, b, acc, 0, 0, 0);
            }
            // oc = q*4+r -> o = oc>>1, c = oc&1: (r0,r1) = (re,im) of o0,
            // (r2,r3) = (re,im) of o1. Pack each pair into one u32 store.
            const int o0 = q * 2, o1 = o0 + 1;
            const int fb = f >> 2;        // 8-elem block index within row
            const int fo = (f & 3) * 2;   // elem offset within block
            const int b0 = (fb < 16) ? (fb ^ o0) : fb;  // per-o bank swizzle
            const int b1 = (fb < 16) ? (fb ^ o1) : fb;
            unsigned int p01 = pack_bf2(acc[0], acc[1]);
            unsigned int p23 = pack_bf2(acc[2], acc[3]);
            *(unsigned int*)&ybuf[(o0 * 16 + nl) * 136 + b0 * 8 + fo] = p01;
            *(unsigned int*)&ybuf[(o1 * 16 + nl) * 136 + b1 * 8 + fo] = p23;
        }
    }
    __syncthreads();

    for (int p = wave; p < 64; p += 4) {
        const int o = p >> 3, nt = p & 7;
        f32x4 acc = {0.f, 0.f, 0.f, 0.f};
#pragma unroll
        for (int kc = 0; kc < 5; kc++) {
            const int bb = kc * 4 + q;
            const int bs = (bb < 16) ? (bb ^ o) : bb;  // same uniform XOR
            bf16x8 a = *(const bf16x8*)&ybuf[(o * 16 + nl) * 136 + bs * 8];
            bf16x8 b = *(const bf16x8*)(B2T + (nt * 16 + nl) * 160 + kc * 32 + q * 8);
            acc = __builtin_amdgcn_mfma_f32_16x16x32_bf16(a, b, acc, 0, 0, 0);
        }
        float* op = out + (size_t)(s0 + q * 4) * 8192 + (o_t * 8 + o) * 128 + nt * 16 + nl;
#pragma unroll
        for (int r = 0; r < 4; r++)
            op[(size_t)r * 8192] = acc[r];
    }
}

extern "C" void kernel_launch(void* const* d_in, const int* in_sizes, int n_in,
                              void* d_out, int out_size, void* d_ws, size_t ws_size,
                              hipStream_t stream) {
    const float* x = (const float*)d_in[0];
    const float* W = (const float*)d_in[1];
    const float* D = (const float*)d_in[2];
    float* out = (float*)d_out;
    char* ws = (char*)d_ws;
    bf16* B1  = (bf16*)(ws + WS_B1);
    bf16* B2T = (bf16*)(ws + WS_B2T);
    bf16* Wm  = (bf16*)(ws + WS_WMAT);
    bf16* X   = (bf16*)(ws + WS_X);

    hipLaunchKernelGGL(init_basis, dim3(96), dim3(256), 0, stream, B1, B2T);
    hipLaunchKernelGGL(init_wmat, dim3(1040), dim3(256), 0, stream, W, Wm);
    hipLaunchKernelGGL(k1_dft, dim3(512), dim3(256), 0, stream, x, D, B1, X);
    hipLaunchKernelGGL(k2_gemm, dim3(2048), dim3(256), 0, stream, X, Wm, B2T, out);
}

// Round 2
// 410.069 us; speedup vs baseline: 1.1843x; 1.1843x over previous
//
#include <hip/hip_runtime.h>

// BlockCirculantLinear via frequency domain:
//   out[s, o*128+t] = ifft_t( sum_j fft(x_d[s,j,:]) * conj(fft(W[o,j,:])) )
// Stages: K1: DFT of x-blocks (MFMA GEMM vs cos/sin basis) -> X[f][s][jc] bf16
//         K2: per-frequency real-ified GEMM over jc (K=128) into LDS Y, then
//             inverse-DFT GEMM (K=160, zero-padded) -> out fp32. No Y in HBM.
// R2 changes (MLP round — K2 was outstanding-load-limited at 52 VGPRs):
//  (a) K2 phase A: 2-slot register double-buffer (f, f+4 per wave), 16
//      independent 16B loads in flight per wave instead of ~2;
//  (b) K2 phase B: B2T fragments hoisted (each wave uses only nt=w, w+4);
//  (c) init_wmat: LDS-staged tau-tiles, coalesced loads, identical fp32 math;
//  (d) K1: grid 512 -> 1024 (j-quarters) for 2x block-level parallelism.

typedef __bf16 bf16;
typedef __bf16 bf16x8 __attribute__((ext_vector_type(8)));
typedef float f32x4 __attribute__((ext_vector_type(4)));

#define PI_F 3.14159265358979323846f

// ws layout (bytes)
#define WS_B1   0u          // [192 fc][128 t] bf16 = 49152
#define WS_B2T  49152u      // [128 t][160 fc] bf16 = 40960
#define WS_WMAT 90112u      // [65 f][128 oc][128 jc] bf16 = 2129920
#define WS_X    2220032u    // [65 f][4096 s][128 jc] bf16 = 68157440

__device__ __forceinline__ unsigned int pack_bf2(float a, float b) {
    unsigned short ra = __builtin_bit_cast(unsigned short, (bf16)a);
    unsigned short rb = __builtin_bit_cast(unsigned short, (bf16)b);
    return (unsigned int)ra | ((unsigned int)rb << 16);
}

// ---------------- init: DFT bases ----------------
// B1[fc][t]: fc=2f+c; c=0 -> cos(2pi f t/128), c=1 -> -sin(...). Rows f>64 zero.
// B2T[t][fc]: inverse-rfft coefficients; fc>=130 zero (padding for K=160 loop).
__global__ __launch_bounds__(256) void init_basis(bf16* __restrict__ B1,
                                                  bf16* __restrict__ B2T) {
    int gid = blockIdx.x * 256 + threadIdx.x;
    if (gid < 192 * 128) {
        int fc = gid >> 7, t = gid & 127;
        int f = fc >> 1;
        float v = 0.f;
        if (f <= 64) {
            int a = (f * t) & 127;
            float ang = a * (PI_F / 64.f);
            v = (fc & 1) ? -__sinf(ang) : __cosf(ang);
        }
        B1[gid] = (bf16)v;
    }
    if (gid < 128 * 160) {
        int t = gid / 160, fc = gid % 160;
        int f = fc >> 1, c = fc & 1;
        float v = 0.f;
        if (f == 0) {
            v = c ? 0.f : (1.f / 128.f);
        } else if (f == 64) {
            v = c ? 0.f : ((t & 1) ? -1.f / 128.f : 1.f / 128.f);
        } else if (f < 64) {
            int a = (f * t) & 127;
            float ang = a * (PI_F / 64.f);
            v = c ? (-2.f / 128.f) * __sinf(ang) : (2.f / 128.f) * __cosf(ang);
        }
        B2T[gid] = (bf16)v;
    }
}

// ---------------- init: frequency-domain weights ----------------
// Wr[o,j,f] = sum_tau W cos, Wi = +sum_tau W sin  (== conj(fft(W)))
// Wmat[f][2o+0][2j+0]=Wr  [2o+0][2j+1]=-Wi  [2o+1][2j+0]=Wi  [2o+1][2j+1]=Wr
// R2: block = (f, 256-row slab). Stage W rows via LDS in 16-tau tiles with
// coalesced 64B-segment loads; compute from LDS ([256][17] pad -> 2-way max).
// Same fp32 accumulation order as R1 -> bit-identical Wmat.
__global__ __launch_bounds__(256) void init_wmat(const float* __restrict__ W,
                                                 bf16* __restrict__ Wm) {
    __shared__ float ct[128], st[128];
    __shared__ float ws[256][17];
    const int tid = threadIdx.x;
    if (tid < 128) {
        float ang = tid * (PI_F / 64.f);
        ct[tid] = __cosf(ang);
        st[tid] = __sinf(ang);
    }
    const int f = blockIdx.x >> 4;           // 16 blocks per f
    const int rb = (blockIdx.x & 15) * 256;  // row base (row = o*64+j)
    const float* wbase = W + (size_t)rb * 128;
    float wr = 0.f, wi = 0.f;
    for (int tb = 0; tb < 8; tb++) {
        __syncthreads();
        // stage rows [rb..rb+256) x tau [tb*16..+16): 1024 float4, coalesced
#pragma unroll
        for (int i = 0; i < 4; i++) {
            int v = i * 256 + tid;
            int row = v >> 2, seg = v & 3;
            float4 t = *(const float4*)(wbase + (size_t)row * 128 + tb * 16 + seg * 4);
            ws[row][seg * 4 + 0] = t.x;
            ws[row][seg * 4 + 1] = t.y;
            ws[row][seg * 4 + 2] = t.z;
            ws[row][seg * 4 + 3] = t.w;
        }
        __syncthreads();
#pragma unroll
        for (int u = 0; u < 16; u++) {
            int tau = tb * 16 + u;
            float w = ws[tid][u];
            int a = (f * tau) & 127;
            wr += w * ct[a];
            wi += w * st[a];
        }
    }
    const int row = rb + tid;
    const int o = row >> 6, j = row & 63;
    bf16* base = Wm + ((size_t)f * 128 + 2 * o) * 128 + 2 * j;
    *(unsigned int*)base         = pack_bf2(wr, -wi);
    *(unsigned int*)(base + 128) = pack_bf2(wi, wr);
}

// ---------------- K1: DFT of x-blocks ----------------
// grid 1024: blockIdx = s_tile(256) * 4 + j_quarter. block 256 (4 waves).
// Per 8-j round: stage x*D (fp32->bf16) to LDS, waves compute live fc n-tiles
// (nt = wave+4t; nt 9..11 are all-zero B1 rows -> skipped; only wave 0 runs
// t=2 for nt=8 which holds f=64), then XOR-1 lane exchange pairs (re,im) and
// stores 16B/lane to X[f][s][jc].
__global__ __launch_bounds__(256) void k1_dft(const float* __restrict__ x,
                                              const float* __restrict__ D,
                                              const bf16* __restrict__ B1,
                                              bf16* __restrict__ X) {
    __shared__ bf16 xs[8][16][136];
    const int tid = threadIdx.x;
    const int wave = tid >> 6, lane = tid & 63;
    const int q = lane >> 4, nl = lane & 15;
    const int s_t = blockIdx.x >> 2, jq = blockIdx.x & 3;
    const int s0 = s_t * 16;
    const bool nt2 = (wave == 0);  // t=2 live only for wave 0 (nt=8)

    // constant B-fragments (B1 rows fc>=144 are all zero -> not loaded)
    bf16x8 bfrag[3][4];
#pragma unroll
    for (int t = 0; t < 2; t++) {
        int nt = wave + 4 * t;
#pragma unroll
        for (int kc = 0; kc < 4; kc++)
            bfrag[t][kc] = *(const bf16x8*)(B1 + (nt * 16 + nl) * 128 + kc * 32 + q * 8);
    }
    if (nt2) {
#pragma unroll
        for (int kc = 0; kc < 4; kc++)
            bfrag[2][kc] = *(const bf16x8*)(B1 + (128 + nl) * 128 + kc * 32 + q * 8);
    }

    for (int grp = 0; grp < 2; grp++) {
        const int jb = jq * 16 + grp * 8;
        __syncthreads();
        {   // stage 8 j-blocks: 8*16*128 fp32 -> bf16 (apply diagonal D)
            const int jl = tid >> 5, ss = (tid >> 1) & 15, th = tid & 1;
            const float* xp = x + (size_t)(s0 + ss) * 8192 + (jb + jl) * 128 + th * 64;
            const float* Dp = D + (jb + jl) * 128 + th * 64;
            bf16* dst = &xs[jl][ss][th * 64];
#pragma unroll
            for (int u = 0; u < 8; u++) {
                float4 a  = *(const float4*)(xp + u * 8);
                float4 b  = *(const float4*)(xp + u * 8 + 4);
                float4 da = *(const float4*)(Dp + u * 8);
                float4 db = *(const float4*)(Dp + u * 8 + 4);
                bf16x8 o;
                o[0] = (bf16)(a.x * da.x); o[1] = (bf16)(a.y * da.y);
                o[2] = (bf16)(a.z * da.z); o[3] = (bf16)(a.w * da.w);
                o[4] = (bf16)(b.x * db.x); o[5] = (bf16)(b.y * db.y);
                o[6] = (bf16)(b.z * db.z); o[7] = (bf16)(b.w * db.w);
                *(bf16x8*)(dst + u * 8) = o;
            }
        }
        __syncthreads();

        f32x4 acc[3][8];
        const f32x4 zero = {0.f, 0.f, 0.f, 0.f};
#pragma unroll
        for (int t = 0; t < 3; t++)
#pragma unroll
            for (int j = 0; j < 8; j++) acc[t][j] = zero;

        // main pass: 2 live n-tiles for every wave (branch-free hot loop)
#pragma unroll
        for (int j = 0; j < 8; j++) {
#pragma unroll
            for (int kc = 0; kc < 4; kc++) {
                bf16x8 a = *(const bf16x8*)&xs[j][nl][kc * 32 + q * 8];
                acc[0][j] = __builtin_amdgcn_mfma_f32_16x16x32_bf16(
                    a, bfrag[0][kc], acc[0][j], 0, 0, 0);
                acc[1][j] = __builtin_amdgcn_mfma_f32_16x16x32_bf16(
                    a, bfrag[1][kc], acc[1][j], 0, 0, 0);
            }
        }
        if (nt2) {  // wave 0 only: nt=8 tile (f=64)
#pragma unroll
            for (int j = 0; j < 8; j++) {
#pragma unroll
                for (int kc = 0; kc < 4; kc++) {
                    bf16x8 a = *(const bf16x8*)&xs[j][nl][kc * 32 + q * 8];
                    acc[2][j] = __builtin_amdgcn_mfma_f32_16x16x32_bf16(
                        a, bfrag[2][kc], acc[2][j], 0, 0, 0);
                }
            }
        }

        // register transpose + store: lane pair (fc even/odd) = (re, im)
        const int par = lane & 1;
#pragma unroll
        for (int t = 0; t < 3; t++) {
            if (t == 2 && !nt2) continue;  // wave-uniform skip of dead tiles
            const int fc = (wave + 4 * t) * 16 + nl;
            const int fpr = fc >> 1;
            const bool wr = (fc < 130);
#pragma unroll
            for (int r = 0; r < 4; r++) {
                float sh[8];
#pragma unroll
                for (int j = 0; j < 8; j++)
                    sh[j] = __shfl_xor(acc[t][j][r], 1);
                unsigned int d0, d1, d2, d3;
                if (!par) {
                    d0 = pack_bf2(acc[t][0][r], sh[0]);
                    d1 = pack_bf2(acc[t][1][r], sh[1]);
                    d2 = pack_bf2(acc[t][2][r], sh[2]);
                    d3 = pack_bf2(acc[t][3][r], sh[3]);
                } else {
                    d0 = pack_bf2(sh[4], acc[t][4][r]);
                    d1 = pack_bf2(sh[5], acc[t][5][r]);
                    d2 = pack_bf2(sh[6], acc[t][6][r]);
                    d3 = pack_bf2(sh[7], acc[t][7][r]);
                }
                if (wr) {
                    char* p = (char*)X + ((size_t)fpr * 4096 + s0 + q * 4 + r) * 256
                              + jb * 4 + par * 16;
                    *(uint4*)p = make_uint4(d0, d1, d2, d3);
                }
            }
        }
    }
}

// ---------------- K2: per-frequency contraction + inverse DFT ----------------
// grid 2048, XCD-swizzled: the 8 o_tiles of one s_tile are 8 CONSECUTIVE
// blocks on ONE XCD, so the shared 266KB X slice is L2-local after first touch.
// Phase A: per wave, slots f = 4k+wave processed as a 2-slot register
//   double-buffer (f and f+4): 16 independent 16B loads in flight per wave
//   (was ~2 at 52 VGPRs -> MLP-bound at 1.1 TB/s). Scatter into LDS
//   Y[o][s][fc] with per-o XOR block swizzle.
// Phase B: B2T frags hoisted (wave uses only nt=w,w+4: 10 frags, 40 VGPR);
//   per (o,h): out[s,t] = Y * B2T (K=160; rows>=130 of B2T are 0).
__global__ __launch_bounds__(256, 4) void k2_gemm(const bf16* __restrict__ X,
                                                  const bf16* __restrict__ Wmat,
                                                  const bf16* __restrict__ B2T,
                                                  float* __restrict__ out) {
    __shared__ bf16 ybuf[8 * 16 * 136 + 32];  // [o][s][fc136] + overrun pad
    const int tid = threadIdx.x;
    const int wave = tid >> 6, lane = tid & 63;
    const int q = lane >> 4, nl = lane & 15;
    // XCD-aware swizzle (bijective: 2048 = 8 XCD * 256 blocks/XCD)
    const int bid = blockIdx.x;
    const int xcd = bid & 7, seq = bid >> 3;
    const int s_t = xcd + 8 * (seq >> 3);
    const int o_t = seq & 7;
    const int s0 = s_t * 16;

    {   // zero (covers fc 130..135 pad + masked freqs)
        unsigned int* yz = (unsigned int*)ybuf;
        for (int i = tid; i < (8 * 16 * 136 + 32) / 2; i += 256) yz[i] = 0u;
    }

    // per-lane fragment base pointers (add f*stride + kc*32)
    const bf16* wp = Wmat + (size_t)(o_t * 16 + nl) * 128 + q * 8;
    const bf16* xp = X + (size_t)(s0 + nl) * 128 + q * 8;

    bf16x8 wa[4], xa[4], wb[4], xb[4];
    auto loadf = [&](int f, bf16x8 (&wf)[4], bf16x8 (&xf)[4]) {
#pragma unroll
        for (int kc = 0; kc < 4; kc++) {
            wf[kc] = *(const bf16x8*)(wp + (size_t)f * 16384 + kc * 32);
            xf[kc] = *(const bf16x8*)(xp + (size_t)f * 524288 + kc * 32);
        }
    };
    auto compute = [&](int f, bf16x8 (&wf)[4], bf16x8 (&xf)[4]) {
        f32x4 acc = {0.f, 0.f, 0.f, 0.f};
#pragma unroll
        for (int kc = 0; kc < 4; kc++)
            acc = __builtin_amdgcn_mfma_f32_16x16x32_bf16(wf[kc], xf[kc], acc, 0, 0, 0);
        // oc = q*4+r -> o = oc>>1: (r0,r1)=(re,im) of o0=2q, (r2,r3) of o1.
        const int o0 = q * 2, o1 = o0 + 1;
        const int fb = f >> 2, fo = (f & 3) * 2;
        const int b0 = (fb < 16) ? (fb ^ o0) : fb;  // per-o bank swizzle
        const int b1 = (fb < 16) ? (fb ^ o1) : fb;
        *(unsigned int*)&ybuf[(o0 * 16 + nl) * 136 + b0 * 8 + fo] = pack_bf2(acc[0], acc[1]);
        *(unsigned int*)&ybuf[(o1 * 16 + nl) * 136 + b1 * 8 + fo] = pack_bf2(acc[2], acc[3]);
    };

    loadf(wave, wa, xa);   // preload slot 0 (overlaps barrier wait)
    __syncthreads();       // zero-init visible

    for (int g = 0; g < 9; g++) {
        const int f0 = g * 8 + wave;
        const int f1 = f0 + 4;
        const int f2 = f0 + 8;
        if (f1 < 65) loadf(f1, wb, xb);
        if (f0 < 65) compute(f0, wa, xa);
        if (f2 < 65) loadf(f2, wa, xa);
        if (f1 < 65) compute(f1, wb, xb);
    }

    // hoist B2T fragments: this wave only ever uses nt = wave, wave+4
    bf16x8 bt[2][5];
#pragma unroll
    for (int h = 0; h < 2; h++) {
        const int nt = wave + 4 * h;
#pragma unroll
        for (int kc = 0; kc < 5; kc++)
            bt[h][kc] = *(const bf16x8*)(B2T + (nt * 16 + nl) * 160 + kc * 32 + q * 8);
    }
    __syncthreads();  // Y complete

#pragma unroll
    for (int o = 0; o < 8; o++) {
#pragma unroll
        for (int h = 0; h < 2; h++) {
            f32x4 acc = {0.f, 0.f, 0.f, 0.f};
#pragma unroll
            for (int kc = 0; kc < 5; kc++) {
                const int bb = kc * 4 + q;
                const int bs = (bb < 16) ? (bb ^ o) : bb;  // same uniform XOR
                bf16x8 a = *(const bf16x8*)&ybuf[(o * 16 + nl) * 136 + bs * 8];
                acc = __builtin_amdgcn_mfma_f32_16x16x32_bf16(a, bt[h][kc], acc, 0, 0, 0);
            }
            const int nt = wave + 4 * h;
            float* op = out + (size_t)(s0 + q * 4) * 8192 + (o_t * 8 + o) * 128 + nt * 16 + nl;
#pragma unroll
            for (int r = 0; r < 4; r++)
                op[(size_t)r * 8192] = acc[r];
        }
    }
}

extern "C" void kernel_launch(void* const* d_in, const int* in_sizes, int n_in,
                              void* d_out, int out_size, void* d_ws, size_t ws_size,
                              hipStream_t stream) {
    const float* x = (const float*)d_in[0];
    const float* W = (const float*)d_in[1];
    const float* D = (const float*)d_in[2];
    float* out = (float*)d_out;
    char* ws = (char*)d_ws;
    bf16* B1  = (bf16*)(ws + WS_B1);
    bf16* B2T = (bf16*)(ws + WS_B2T);
    bf16* Wm  = (bf16*)(ws + WS_WMAT);
    bf16* X   = (bf16*)(ws + WS_X);

    hipLaunchKernelGGL(init_basis, dim3(96), dim3(256), 0, stream, B1, B2T);
    hipLaunchKernelGGL(init_wmat, dim3(1040), dim3(256), 0, stream, W, Wm);
    hipLaunchKernelGGL(k1_dft, dim3(1024), dim3(256), 0, stream, x, D, B1, X);
    hipLaunchKernelGGL(k2_gemm, dim3(2048), dim3(256), 0, stream, X, Wm, B2T, out);
}

// Round 5
// 374.021 us; speedup vs baseline: 1.2985x; 1.0964x over previous
//
#include <hip/hip_runtime.h>

// BlockCirculantLinear via frequency domain:
//   out[s, o*128+t] = ifft_t( sum_j fft(x_d[s,j,:]) * conj(fft(W[o,j,:])) )
// Stages: K1: DFT of x-blocks (MFMA GEMM vs cos/sin basis) -> X[f][s][jc] bf16
//         K2: per-frequency real-ified GEMM over jc (K=128) into LDS Y, then
//             inverse-DFT GEMM (K=160, zero-padded) -> out fp32. No Y in HBM.
// R5 changes (k2 phase A conformed to the PROVEN global_load_lds discipline):
//   R3/R4's wave-private counted-vmcnt pipeline lacked an s_barrier between
//   the vmcnt wait and the ds_read of the staged buffer — every verified
//   global_load_lds pattern (m97/m201/AITER) has one (DMA LDS-write
//   visibility). Phase A is now block-cooperative lockstep:
//     per group g: issue dma(g+1)+loadW(g+1) | sched_barrier |
//                  s_waitcnt vmcnt(8) | s_barrier | compute(g).
//   Exactly 8 vmem ops per iteration -> vmcnt(8) counting is robust to
//   within-iteration reorder. Clamped redundant loads replace divergent
//   guards; no barrier is ever under a divergent branch.

typedef __bf16 bf16;
typedef __bf16 bf16x8 __attribute__((ext_vector_type(8)));
typedef float f32x4 __attribute__((ext_vector_type(4)));

#define PI_F 3.14159265358979323846f

// ws layout (bytes)
#define WS_B1   0u          // [192 fc][128 t] bf16 = 49152
#define WS_B2T  49152u      // [128 t][160 fc] bf16 = 40960
#define WS_WMAT 90112u      // [65 f][128 oc][128 jc] bf16 = 2129920
#define WS_X    2220032u    // [65 f][4096 s][128 jc] bf16 = 68157440

#define GLOAD_LDS16(g, l) __builtin_amdgcn_global_load_lds( \
    (const __attribute__((address_space(1))) unsigned int*)(g), \
    (__attribute__((address_space(3))) unsigned int*)(l), 16, 0, 0)

__device__ __forceinline__ unsigned int pack_bf2(float a, float b) {
    unsigned short ra = __builtin_bit_cast(unsigned short, (bf16)a);
    unsigned short rb = __builtin_bit_cast(unsigned short, (bf16)b);
    return (unsigned int)ra | ((unsigned int)rb << 16);
}

// ---------------- init: DFT bases ----------------
// B1[fc][t]: fc=2f+c; c=0 -> cos(2pi f t/128), c=1 -> -sin(...). Rows f>64 zero.
// B2T[t][fc]: inverse-rfft coefficients; fc>=130 zero (padding for K=160 loop).
__global__ __launch_bounds__(256) void init_basis(bf16* __restrict__ B1,
                                                  bf16* __restrict__ B2T) {
    int gid = blockIdx.x * 256 + threadIdx.x;
    if (gid < 192 * 128) {
        int fc = gid >> 7, t = gid & 127;
        int f = fc >> 1;
        float v = 0.f;
        if (f <= 64) {
            int a = (f * t) & 127;
            float ang = a * (PI_F / 64.f);
            v = (fc & 1) ? -__sinf(ang) : __cosf(ang);
        }
        B1[gid] = (bf16)v;
    }
    if (gid < 128 * 160) {
        int t = gid / 160, fc = gid % 160;
        int f = fc >> 1, c = fc & 1;
        float v = 0.f;
        if (f == 0) {
            v = c ? 0.f : (1.f / 128.f);
        } else if (f == 64) {
            v = c ? 0.f : ((t & 1) ? -1.f / 128.f : 1.f / 128.f);
        } else if (f < 64) {
            int a = (f * t) & 127;
            float ang = a * (PI_F / 64.f);
            v = c ? (-2.f / 128.f) * __sinf(ang) : (2.f / 128.f) * __cosf(ang);
        }
        B2T[gid] = (bf16)v;
    }
}

// ---------------- init: frequency-domain weights ----------------
// Wr[o,j,f] = sum_tau W cos, Wi = +sum_tau W sin  (== conj(fft(W)))
// Wmat[f][2o+0][2j+0]=Wr  [2o+0][2j+1]=-Wi  [2o+1][2j+0]=Wi  [2o+1][2j+1]=Wr
__global__ __launch_bounds__(256) void init_wmat(const float* __restrict__ W,
                                                 bf16* __restrict__ Wm) {
    __shared__ float ct[128], st[128];
    __shared__ float ws[256][17];
    const int tid = threadIdx.x;
    if (tid < 128) {
        float ang = tid * (PI_F / 64.f);
        ct[tid] = __cosf(ang);
        st[tid] = __sinf(ang);
    }
    const int f = blockIdx.x >> 4;           // 16 blocks per f
    const int rb = (blockIdx.x & 15) * 256;  // row base (row = o*64+j)
    const float* wbase = W + (size_t)rb * 128;
    float wr = 0.f, wi = 0.f;
    for (int tb = 0; tb < 8; tb++) {
        __syncthreads();
        // stage rows [rb..rb+256) x tau [tb*16..+16): 1024 float4, coalesced
#pragma unroll
        for (int i = 0; i < 4; i++) {
            int v = i * 256 + tid;
            int row = v >> 2, seg = v & 3;
            float4 t = *(const float4*)(wbase + (size_t)row * 128 + tb * 16 + seg * 4);
            ws[row][seg * 4 + 0] = t.x;
            ws[row][seg * 4 + 1] = t.y;
            ws[row][seg * 4 + 2] = t.z;
            ws[row][seg * 4 + 3] = t.w;
        }
        __syncthreads();
#pragma unroll
        for (int u = 0; u < 16; u++) {
            int tau = tb * 16 + u;
            float w = ws[tid][u];
            int a = (f * tau) & 127;
            wr += w * ct[a];
            wi += w * st[a];
        }
    }
    const int row = rb + tid;
    const int o = row >> 6, j = row & 63;
    bf16* base = Wm + ((size_t)f * 128 + 2 * o) * 128 + 2 * j;
    *(unsigned int*)base         = pack_bf2(wr, -wi);
    *(unsigned int*)(base + 128) = pack_bf2(wi, wr);
}

// ---------------- K1: DFT of x-blocks ----------------
// grid 1024: blockIdx = s_tile(256) * 4 + j_quarter. block 256 (4 waves).
__global__ __launch_bounds__(256) void k1_dft(const float* __restrict__ x,
                                              const float* __restrict__ D,
                                              const bf16* __restrict__ B1,
                                              bf16* __restrict__ X) {
    __shared__ bf16 xs[8][16][136];
    const int tid = threadIdx.x;
    const int wave = tid >> 6, lane = tid & 63;
    const int q = lane >> 4, nl = lane & 15;
    const int s_t = blockIdx.x >> 2, jq = blockIdx.x & 3;
    const int s0 = s_t * 16;
    const bool nt2 = (wave == 0);  // t=2 live only for wave 0 (nt=8)

    // constant B-fragments (B1 rows fc>=144 are all zero -> not loaded)
    bf16x8 bfrag[3][4];
#pragma unroll
    for (int t = 0; t < 2; t++) {
        int nt = wave + 4 * t;
#pragma unroll
        for (int kc = 0; kc < 4; kc++)
            bfrag[t][kc] = *(const bf16x8*)(B1 + (nt * 16 + nl) * 128 + kc * 32 + q * 8);
    }
    if (nt2) {
#pragma unroll
        for (int kc = 0; kc < 4; kc++)
            bfrag[2][kc] = *(const bf16x8*)(B1 + (128 + nl) * 128 + kc * 32 + q * 8);
    }

    for (int grp = 0; grp < 2; grp++) {
        const int jb = jq * 16 + grp * 8;
        __syncthreads();
        {   // stage 8 j-blocks: 8*16*128 fp32 -> bf16 (apply diagonal D)
            const int jl = tid >> 5, ss = (tid >> 1) & 15, th = tid & 1;
            const float* xp = x + (size_t)(s0 + ss) * 8192 + (jb + jl) * 128 + th * 64;
            const float* Dp = D + (jb + jl) * 128 + th * 64;
            bf16* dst = &xs[jl][ss][th * 64];
#pragma unroll
            for (int u = 0; u < 8; u++) {
                float4 a  = *(const float4*)(xp + u * 8);
                float4 b  = *(const float4*)(xp + u * 8 + 4);
                float4 da = *(const float4*)(Dp + u * 8);
                float4 db = *(const float4*)(Dp + u * 8 + 4);
                bf16x8 o;
                o[0] = (bf16)(a.x * da.x); o[1] = (bf16)(a.y * da.y);
                o[2] = (bf16)(a.z * da.z); o[3] = (bf16)(a.w * da.w);
                o[4] = (bf16)(b.x * db.x); o[5] = (bf16)(b.y * db.y);
                o[6] = (bf16)(b.z * db.z); o[7] = (bf16)(b.w * db.w);
                *(bf16x8*)(dst + u * 8) = o;
            }
        }
        __syncthreads();

        f32x4 acc[3][8];
        const f32x4 zero = {0.f, 0.f, 0.f, 0.f};
#pragma unroll
        for (int t = 0; t < 3; t++)
#pragma unroll
            for (int j = 0; j < 8; j++) acc[t][j] = zero;

        // main pass: 2 live n-tiles for every wave (branch-free hot loop)
#pragma unroll
        for (int j = 0; j < 8; j++) {
#pragma unroll
            for (int kc = 0; kc < 4; kc++) {
                bf16x8 a = *(const bf16x8*)&xs[j][nl][kc * 32 + q * 8];
                acc[0][j] = __builtin_amdgcn_mfma_f32_16x16x32_bf16(
                    a, bfrag[0][kc], acc[0][j], 0, 0, 0);
                acc[1][j] = __builtin_amdgcn_mfma_f32_16x16x32_bf16(
                    a, bfrag[1][kc], acc[1][j], 0, 0, 0);
            }
        }
        if (nt2) {  // wave 0 only: nt=8 tile (f=64)
#pragma unroll
            for (int j = 0; j < 8; j++) {
#pragma unroll
                for (int kc = 0; kc < 4; kc++) {
                    bf16x8 a = *(const bf16x8*)&xs[j][nl][kc * 32 + q * 8];
                    acc[2][j] = __builtin_amdgcn_mfma_f32_16x16x32_bf16(
                        a, bfrag[2][kc], acc[2][j], 0, 0, 0);
                }
            }
        }

        // register transpose + store: lane pair (fc even/odd) = (re, im)
        const int par = lane & 1;
#pragma unroll
        for (int t = 0; t < 3; t++) {
            if (t == 2 && !nt2) continue;  // wave-uniform skip of dead tiles
            const int fc = (wave + 4 * t) * 16 + nl;
            const int fpr = fc >> 1;
            const bool wr = (fc < 130);
#pragma unroll
            for (int r = 0; r < 4; r++) {
                float sh[8];
#pragma unroll
                for (int j = 0; j < 8; j++)
                    sh[j] = __shfl_xor(acc[t][j][r], 1);
                unsigned int d0, d1, d2, d3;
                if (!par) {
                    d0 = pack_bf2(acc[t][0][r], sh[0]);
                    d1 = pack_bf2(acc[t][1][r], sh[1]);
                    d2 = pack_bf2(acc[t][2][r], sh[2]);
                    d3 = pack_bf2(acc[t][3][r], sh[3]);
                } else {
                    d0 = pack_bf2(sh[4], acc[t][4][r]);
                    d1 = pack_bf2(sh[5], acc[t][5][r]);
                    d2 = pack_bf2(sh[6], acc[t][6][r]);
                    d3 = pack_bf2(sh[7], acc[t][7][r]);
                }
                if (wr) {
                    char* p = (char*)X + ((size_t)fpr * 4096 + s0 + q * 4 + r) * 256
                              + jb * 4 + par * 16;
                    *(uint4*)p = make_uint4(d0, d1, d2, d3);
                }
            }
        }
    }
}

// ---------------- K2: per-frequency contraction + inverse DFT ----------------
// grid 2048, XCD-swizzled (8 o_tiles of one s_tile consecutive on one XCD).
// Phase A (m201-discipline pipeline): 17 groups; group g = freqs {4g+wave}.
//   Per group: issue dma(g+1) (4x global_load_lds, 4KB wave slice into
//   double-buffered LDS) + loadW(g+1) (4 register frags) | sched_barrier |
//   s_waitcnt vmcnt(8) (retires group g's 8 ops, leaves group g+1's 8 in
//   flight) | s_barrier (DMA LDS-write visibility — the piece R3/R4 lacked) |
//   compute(g). Source chunks pre-swizzled (c ^= s&7) so swizzled
//   ds_read_b128 is conflict-free (rule #21 both-sides). Scatter into LDS
//   Y[o][s][fc] with per-o XOR block swizzle.
// Phase B: nt = 2*wave+h (full 128B out lines); B2T frags hoisted;
//   per (o,h): out[s,t] = Y * B2T (K=160; B2T rows>=130 are 0).
__global__ __launch_bounds__(256, 2) void k2_gemm(const bf16* __restrict__ X,
                                                  const bf16* __restrict__ Wmat,
                                                  const bf16* __restrict__ B2T,
                                                  float* __restrict__ out) {
    __shared__ __align__(16) bf16 ybuf[8 * 16 * 136 + 32];  // [o][s][fc136] + pad
    __shared__ __align__(16) bf16 xstage[2][4][2048];       // [buf][wave][16s x 128jc swz]
    const int tid = threadIdx.x;
    const int wave = tid >> 6, lane = tid & 63;
    const int q = lane >> 4, nl = lane & 15;
    // XCD-aware swizzle (bijective: 2048 = 8 XCD * 256 blocks/XCD)
    const int bid = blockIdx.x;
    const int xcd = bid & 7, seq = bid >> 3;
    const int s_t = xcd + 8 * (seq >> 3);
    const int o_t = seq & 7;
    const int s0 = s_t * 16;

    {   // zero (covers fc 130..135 pad + masked freqs)
        unsigned int* yz = (unsigned int*)ybuf;
        for (int i = tid; i < (8 * 16 * 136 + 32) / 2; i += 256) yz[i] = 0u;
    }
    __syncthreads();

    // per-lane DMA source byte offsets within one X[f] slice (swizzled chunks)
    int soff[4];
#pragma unroll
    for (int r = 0; r < 4; r++) {
        int s_loc = r * 4 + (lane >> 4);
        int cg = (lane & 15) ^ (s_loc & 7);
        soff[r] = (s0 + s_loc) * 256 + cg * 16;
    }
    const char* Xb = (const char*)X;

    // group g -> wave frequency f = 4g+wave, clamped (redundant load) past 64
    auto dmaG = [&](int g) {
        int f = g * 4 + wave;
        if (f > 64) f = 64;
        const char* src = Xb + (size_t)f * 1048576u;
        char* dst = (char*)&xstage[g & 1][wave][0];
#pragma unroll
        for (int r = 0; r < 4; r++)
            GLOAD_LDS16(src + soff[r], dst + r * 1024);
    };
    const bf16* wp = Wmat + (size_t)(o_t * 16 + nl) * 128 + q * 8;
    auto loadWG = [&](int g, bf16x8(&wf)[4]) {
        int f = g * 4 + wave;
        if (f > 64) f = 64;
#pragma unroll
        for (int kc = 0; kc < 4; kc++)
            wf[kc] = *(const bf16x8*)(wp + (size_t)f * 16384 + kc * 32);
    };
    auto comp = [&](int g, const bf16x8(&wf)[4]) {
        const int f = g * 4 + wave;
        if (f < 65) {
            const bf16* stg = &xstage[g & 1][wave][0];
            f32x4 acc = {0.f, 0.f, 0.f, 0.f};
#pragma unroll
            for (int kc = 0; kc < 4; kc++) {
                const int c = (kc * 4 + q) ^ (nl & 7);
                bf16x8 b = *(const bf16x8*)(stg + nl * 128 + c * 8);
                acc = __builtin_amdgcn_mfma_f32_16x16x32_bf16(wf[kc], b, acc, 0, 0, 0);
            }
            // oc = q*4+r -> o = oc>>1: (r0,r1)=(re,im) of o0=2q, (r2,r3) of o1.
            const int o0 = q * 2, o1 = o0 + 1;
            const int fb = f >> 2, fo = (f & 3) * 2;
            const int b0 = (fb < 16) ? (fb ^ o0) : fb;  // per-o bank swizzle
            const int b1 = (fb < 16) ? (fb ^ o1) : fb;
            *(unsigned int*)&ybuf[(o0 * 16 + nl) * 136 + b0 * 8 + fo] = pack_bf2(acc[0], acc[1]);
            *(unsigned int*)&ybuf[(o1 * 16 + nl) * 136 + b1 * 8 + fo] = pack_bf2(acc[2], acc[3]);
        }
    };

    bf16x8 wcur[4], wnxt[4];
    dmaG(0);
    loadWG(0, wcur);
    // pin prologue group (8 vmem ops) before iteration 0's group
    asm volatile("" ::: "memory");
    __builtin_amdgcn_sched_barrier(0);
    for (int g = 0; g < 17; g++) {
        if (g < 16) {
            dmaG(g + 1);
            loadWG(g + 1, wnxt);
        }
        __builtin_amdgcn_sched_barrier(0);
        if (g < 16)
            asm volatile("s_waitcnt vmcnt(8)" ::: "memory");
        else
            asm volatile("s_waitcnt vmcnt(0)" ::: "memory");
        __builtin_amdgcn_s_barrier();   // DMA LDS-write visibility + lockstep
        __builtin_amdgcn_sched_barrier(0);
        comp(g, wcur);
#pragma unroll
        for (int kc = 0; kc < 4; kc++) wcur[kc] = wnxt[kc];
        __builtin_amdgcn_sched_barrier(0);
    }

    // hoist B2T fragments: this wave only uses nt = 2*wave, 2*wave+1
    bf16x8 bt[2][5];
#pragma unroll
    for (int h = 0; h < 2; h++) {
        const int nt = wave * 2 + h;
#pragma unroll
        for (int kc = 0; kc < 5; kc++)
            bt[h][kc] = *(const bf16x8*)(B2T + (nt * 16 + nl) * 160 + kc * 32 + q * 8);
    }
    __syncthreads();  // Y complete

#pragma unroll
    for (int o = 0; o < 8; o++) {
#pragma unroll
        for (int h = 0; h < 2; h++) {
            f32x4 acc = {0.f, 0.f, 0.f, 0.f};
#pragma unroll
            for (int kc = 0; kc < 5; kc++) {
                const int bb = kc * 4 + q;
                const int bs = (bb < 16) ? (bb ^ o) : bb;  // same uniform XOR
                bf16x8 a = *(const bf16x8*)&ybuf[(o * 16 + nl) * 136 + bs * 8];
                acc = __builtin_amdgcn_mfma_f32_16x16x32_bf16(a, bt[h][kc], acc, 0, 0, 0);
            }
            const int nt = wave * 2 + h;
            float* op = out + (size_t)(s0 + q * 4) * 8192 + (o_t * 8 + o) * 128 + nt * 16 + nl;
#pragma unroll
            for (int r = 0; r < 4; r++)
                op[(size_t)r * 8192] = acc[r];
        }
    }
}

extern "C" void kernel_launch(void* const* d_in, const int* in_sizes, int n_in,
                              void* d_out, int out_size, void* d_ws, size_t ws_size,
                              hipStream_t stream) {
    const float* x = (const float*)d_in[0];
    const float* W = (const float*)d_in[1];
    const float* D = (const float*)d_in[2];
    float* out = (float*)d_out;
    char* ws = (char*)d_ws;
    bf16* B1  = (bf16*)(ws + WS_B1);
    bf16* B2T = (bf16*)(ws + WS_B2T);
    bf16* Wm  = (bf16*)(ws + WS_WMAT);
    bf16* X   = (bf16*)(ws + WS_X);

    hipLaunchKernelGGL(init_basis, dim3(96), dim3(256), 0, stream, B1, B2T);
    hipLaunchKernelGGL(init_wmat, dim3(1040), dim3(256), 0, stream, W, Wm);
    hipLaunchKernelGGL(k1_dft, dim3(1024), dim3(256), 0, stream, x, D, B1, X);
    hipLaunchKernelGGL(k2_gemm, dim3(2048), dim3(256), 0, stream, X, Wm, B2T, out);
}